// Round 1
// 879.153 us; speedup vs baseline: 1.0204x; 1.0204x over previous
//
#include <hip/hip_runtime.h>

#define B_DIM 64
#define N_TOK 4096
#define C_DIM 512
#define C4 128                  // C_DIM / 4 (float4 per row)
#define NUM_KEEP 2458           // ceil(4096 * 0.6)
#define NON_KEEP 1638           // N_TOK - NUM_KEEP
#define SPLITS 32
#define PER_SPLIT 52            // ceil(NON_KEEP / SPLITS)
#define WSUM_BLOCKS (B_DIM * SPLITS / 4)     // 512 blocks, 4 splits each (512 thr)
#define GATHER_BLOCKS 2048
#define GATHER_GROUPS (GATHER_BLOCKS * 4)    // 8192 row-slots per sweep
#define TOTAL_SEL_ROWS (B_DIM * NUM_KEEP)    // 157312

typedef float f32x4_t __attribute__((ext_vector_type(4)));

__device__ __forceinline__ float4 nt_load4(const float4* p) {
    f32x4_t v = __builtin_nontemporal_load((const f32x4_t*)p);
    return make_float4(v.x, v.y, v.z, v.w);
}
__device__ __forceinline__ void nt_store4(float4* p, float4 v) {
    f32x4_t w = {v.x, v.y, v.z, v.w};
    __builtin_nontemporal_store(w, (f32x4_t*)p);
}

// ---------------------------------------------------------------------------
// Rank-by-counting replaces the bitonic sort.
// key64 = (desc-transformed score bits << 32) | index  -> total order, stable
// (score desc, index asc on ties) == jnp.argsort(-score) semantics.
// Grid: B*4 blocks x 256 threads. Each block stages all 4096 keys of its
// batch in LDS, owns a contiguous 1024-element quarter (4 elems/thread),
// and computes exact ranks with broadcast ulonglong2 reads (conflict-free).
// One barrier total; full chip (256 blocks on 256 CUs).
// ---------------------------------------------------------------------------
__global__ __launch_bounds__(256) void ts_rank_kernel(
    const float* __restrict__ ax, const float* __restrict__ ay,
    int* __restrict__ order, float* __restrict__ svals,
    float* __restrict__ mask)
{
    __shared__ __align__(16) unsigned long long keys[N_TOK];   // 32 KB
    const int blk = blockIdx.x;
    const int b   = blk >> 2;
    const int sp  = blk & 3;          // which 1024-element quarter we own
    const int tid = threadIdx.x;

    const float* axb = ax + b * N_TOK;
    const float* ayb = ay + b * N_TOK;

    unsigned long long myk[4];
    float ms[4];
    #pragma unroll
    for (int k = 0; k < 16; ++k) {
        int i = k * 256 + tid;
        float s = axb[i] + ayb[i];
        unsigned u = __float_as_uint(s);
        // descending-order key: larger score -> smaller key
        unsigned kd = (u & 0x80000000u) ? u : ~(u | 0x80000000u);
        unsigned long long key = ((unsigned long long)kd << 32) | (unsigned)i;
        keys[i] = key;
        if ((k >> 2) == sp) { myk[k & 3] = key; ms[k & 3] = s; }
    }
    __syncthreads();

    // rank = number of strictly-smaller keys; 8 independent accumulators to
    // keep the addc chains off the critical path.
    int ra0 = 0, ra1 = 0, ra2 = 0, ra3 = 0;
    int rb0 = 0, rb1 = 0, rb2 = 0, rb3 = 0;
    const ulonglong2* kp = (const ulonglong2*)keys;
    #pragma unroll 4
    for (int j = 0; j < N_TOK / 2; ++j) {
        ulonglong2 kk = kp[j];          // broadcast read, bank-conflict-free
        ra0 += (kk.x < myk[0]); rb0 += (kk.y < myk[0]);
        ra1 += (kk.x < myk[1]); rb1 += (kk.y < myk[1]);
        ra2 += (kk.x < myk[2]); rb2 += (kk.y < myk[2]);
        ra3 += (kk.x < myk[3]); rb3 += (kk.y < myk[3]);
    }
    int rank[4] = {ra0 + rb0, ra1 + rb1, ra2 + rb2, ra3 + rb3};

    #pragma unroll
    for (int e = 0; e < 4; ++e) {
        int i = sp * 1024 + e * 256 + tid;     // coalesced in i
        int r = rank[e];
        order[b * N_TOK + r] = i;              // scatter (L2-absorbed, 16KB window)
        svals[b * N_TOK + r] = ms[e];
        mask [b * N_TOK + i] = (r < NUM_KEEP) ? 1.0f : 0.0f;
    }
}

// ---------------------------------------------------------------------------
// Softmax over the (already sorted-descending) tail scores.
// svals[b][NUM_KEEP] is the tail max. Contiguous reads; tiny.
// ---------------------------------------------------------------------------
__global__ __launch_bounds__(512) void ts_weights_kernel(
    const float* __restrict__ svals, float* __restrict__ weights)
{
    __shared__ float red[8];
    __shared__ float sinv;
    const int b = blockIdx.x;
    const int tid = threadIdx.x;
    const float m = svals[b * N_TOK + NUM_KEEP];

    float local = 0.f;
    for (int p = tid; p < NON_KEEP; p += 512) {
        float e = expf(svals[b * N_TOK + NUM_KEEP + p] - m);
        weights[b * NON_KEEP + p] = e;         // unnormalized for now
        local += e;
    }
    for (int off = 32; off > 0; off >>= 1) local += __shfl_down(local, off);
    if ((tid & 63) == 0) red[tid >> 6] = local;
    __syncthreads();
    if (tid == 0) {
        float s = 0.f;
        #pragma unroll
        for (int w = 0; w < 8; ++w) s += red[w];
        sinv = 1.0f / s;
    }
    __syncthreads();
    const float inv = sinv;
    for (int p = tid; p < NON_KEEP; p += 512)
        weights[b * NON_KEEP + p] *= inv;
}

// ---------------------------------------------------------------------------
// Fused heavy kernel: first WSUM_BLOCKS blocks do the weighted tail sum
// (dispatched first so the serial accumulation overlaps the gather stream),
// remaining GATHER_BLOCKS blocks grid-stride the select_tokens copy.
// All token/sel traffic is nontemporal (streamed exactly once).
// ---------------------------------------------------------------------------
__global__ __launch_bounds__(512) void ts_heavy_kernel(
    const float4* __restrict__ tokens, const int* __restrict__ order,
    const float* __restrict__ weights, float4* __restrict__ sel,
    float4* __restrict__ partials)
{
    const int tid  = threadIdx.x;
    const int g    = tid >> 7;        // 128-lane group: 0..3
    const int lane = tid & 127;       // float4 lane over C=512

    if (blockIdx.x < WSUM_BLOCKS) {
        int split = blockIdx.x * 4 + g;            // 0..B*SPLITS-1
        int b = split >> 5;                        // / SPLITS
        int s = split & (SPLITS - 1);
        int j0 = s * PER_SPLIT;
        int j1 = j0 + PER_SPLIT; if (j1 > NON_KEEP) j1 = NON_KEEP;
        const int*   ob = order + b * N_TOK + NUM_KEEP;
        const float* wb = weights + b * NON_KEEP;
        float4 acc = make_float4(0.f, 0.f, 0.f, 0.f);
        #pragma unroll 2
        for (int j = j0; j < j1; ++j) {
            int idx = ob[j];
            float w = wb[j];
            float4 t = nt_load4(tokens + ((long long)(b * N_TOK) + idx) * C4 + lane);
            acc.x += w * t.x; acc.y += w * t.y;
            acc.z += w * t.z; acc.w += w * t.w;
        }
        partials[(long long)split * C4 + lane] = acc;   // split == b*SPLITS+s
    } else {
        int grp = (blockIdx.x - WSUM_BLOCKS) * 4 + g;   // 0..GATHER_GROUPS-1
        for (int row = grp; row < TOTAL_SEL_ROWS; row += GATHER_GROUPS) {
            int b = row / NUM_KEEP;                     // magic-mul div
            int k = row - b * NUM_KEEP;
            int idx = order[b * N_TOK + k];             // broadcast 4B load
            float4 v = nt_load4(tokens + ((long long)(b * N_TOK) + idx) * C4 + lane);
            nt_store4(sel + (long long)row * C4 + lane, v);
        }
    }
}

__global__ __launch_bounds__(128) void ts_reduce_kernel(
    const float4* __restrict__ partials, float4* __restrict__ extra)
{
    int b = blockIdx.x;
    int lane = threadIdx.x;
    float4 acc = make_float4(0.f, 0.f, 0.f, 0.f);
    #pragma unroll
    for (int s = 0; s < SPLITS; ++s) {
        float4 t = partials[(long long)(b * SPLITS + s) * C4 + lane];
        acc.x += t.x; acc.y += t.y; acc.z += t.z; acc.w += t.w;
    }
    extra[b * C4 + lane] = acc;
}

extern "C" void kernel_launch(void* const* d_in, const int* in_sizes, int n_in,
                              void* d_out, int out_size, void* d_ws, size_t ws_size,
                              hipStream_t stream) {
    const float* tokens = (const float*)d_in[0];   // (64, 4096, 512) f32
    const float* ax     = (const float*)d_in[1];   // (64, 4096) f32
    const float* ay     = (const float*)d_in[2];   // (64, 4096) f32

    float* out   = (float*)d_out;
    float* sel   = out;                                          // 64*2458*512
    float* extra = out + (long long)B_DIM * NUM_KEEP * C_DIM;    // 64*512
    float* mask  = extra + B_DIM * C_DIM;                        // 64*4096

    char* ws = (char*)d_ws;
    int*   order    = (int*)ws;                                  // 1 MB
    float* svals    = (float*)(ws + (1u << 20));                 // 1 MB
    float* weights  = (float*)(ws + (2u << 20));                 // 419 KB
    float* partials = (float*)(ws + ((2u << 20) + (1u << 19)));  // 4 MB @ 2.5MB

    ts_rank_kernel<<<B_DIM * 4, 256, 0, stream>>>(ax, ay, order, svals, mask);
    ts_weights_kernel<<<B_DIM, 512, 0, stream>>>(svals, weights);
    ts_heavy_kernel<<<WSUM_BLOCKS + GATHER_BLOCKS, 512, 0, stream>>>(
        (const float4*)tokens, order, weights, (float4*)sel, (float4*)partials);
    ts_reduce_kernel<<<B_DIM, 128, 0, stream>>>(
        (const float4*)partials, (float4*)extra);
}